// Round 1
// baseline (3460.036 us; speedup 1.0000x reference)
//
#include <hip/hip_runtime.h>
#include <hip/hip_bf16.h>
#include <math.h>

// Problem constants (fixed by setup_inputs)
#define BB 128
#define DD 512
#define HH 1024
#define NB 32     // num_coeff_per_dim
#define MM 63     // 2N-1 simpson points
#define TT 16
#define ITERS 10

// ws header offsets (floats)
#define OFF_PHIF   0        // 32*63
#define OFF_Q      2048     // 63*32
#define OFF_U      4096     // 32
#define OFF_TTRUE  4160     // 63
#define OFF_PHIOUT 4224     // 32*16
#define HDR        8192
#define OFF_P      HDR                    // B*H*32 = 4194304 floats
#define OFF_BCUR   (HDR + BB*HH*NB)       // B*D*32 = 2097152 floats

// ---------------------------------------------------------------------------
// Setup: t grids, Phi_f, Phi_inv (double GJ), Q = R@Phi_inv, u, Phi_out
// ---------------------------------------------------------------------------
__global__ void setup_kernel(const float* __restrict__ t_span,
                             float* __restrict__ ws) {
    __shared__ double tsim[MM];
    __shared__ double ttrue_d[MM];
    __shared__ double wid[31];
    __shared__ double phid[NB * MM];   // Phi_f in double
    __shared__ double aug[NB * 64];    // [Phi | I] augmented
    __shared__ double mlt[NB];
    __shared__ double Rl[MM * NB];
    __shared__ int    piv_s;
    __shared__ double pv_s;

    const int t = threadIdx.x;  // 64 threads
    const double PI = 3.14159265358979323846;
    const double t0 = (double)t_span[0];
    const double t1 = (double)t_span[TT - 1];

    // t_simpsons and t_true
    if (t < MM) {
        double v;
        if ((t & 1) == 0) {
            int j = t >> 1;
            v = -cos(PI * (double)j / (double)(NB - 1));
        } else {
            int i = t >> 1;
            double a = -cos(PI * (double)i / (double)(NB - 1));
            double b = -cos(PI * (double)(i + 1) / (double)(NB - 1));
            v = 0.5 * (a + b);
        }
        tsim[t] = v;
        ttrue_d[t] = t0 + 0.5 * (t1 - t0) * (v + 1.0);
    }
    __syncthreads();
    if (t < 31) wid[t] = (ttrue_d[2 * t + 2] - ttrue_d[2 * t]) / 6.0;
    if (t < MM) ws[OFF_TTRUE + t] = (float)ttrue_d[t];

    // Phi_f recurrence (thread per m)
    if (t < MM) {
        double x = tsim[t];
        double r0 = 1.0, r1 = x;
        phid[0 * MM + t] = r0;
        phid[1 * MM + t] = r1;
        for (int n = 2; n < NB; n++) {
            double r2 = 2.0 * x * r1 - r0;
            phid[n * MM + t] = r2;
            r0 = r1; r1 = r2;
        }
    }
    __syncthreads();
    for (int f = t; f < NB * MM; f += 64) ws[OFF_PHIF + f] = (float)phid[f];

    // augmented [Phi | I], Phi[r][c] = phid[r*MM + 2c]
    for (int f = t; f < NB * 64; f += 64) {
        int r = f >> 6, c = f & 63;
        double v;
        if (c < NB) v = phid[r * MM + 2 * c];
        else        v = ((c - NB) == r) ? 1.0 : 0.0;
        aug[f] = v;
    }
    __syncthreads();

    // Gauss-Jordan with partial pivoting; thread t owns column t
    for (int k = 0; k < NB; k++) {
        if (t == 0) {
            int p = k;
            double best = fabs(aug[k * 64 + k]);
            for (int r = k + 1; r < NB; r++) {
                double v = fabs(aug[r * 64 + k]);
                if (v > best) { best = v; p = r; }
            }
            piv_s = p;
        }
        __syncthreads();
        int p = piv_s;
        if (p != k) {
            double tmp = aug[k * 64 + t];
            aug[k * 64 + t] = aug[p * 64 + t];
            aug[p * 64 + t] = tmp;
        }
        __syncthreads();
        if (t == 0) pv_s = aug[k * 64 + k];
        __syncthreads();
        aug[k * 64 + t] /= pv_s;
        __syncthreads();
        if (t < NB) mlt[t] = aug[t * 64 + k];
        __syncthreads();
        for (int r = 0; r < NB; r++) {
            if (r != k) aug[r * 64 + t] -= mlt[r] * aug[k * 64 + t];
        }
        __syncthreads();
    }
    // Phi_inv[i][j] = aug[i*64 + 32 + j]

    // R[m][i] = sum_{i'<i} simpson weight of point m in interval i'
    if (t < MM) {
        double acc = 0.0;
        Rl[t * NB + 0] = 0.0;
        for (int i = 1; i < NB; i++) {
            int ip = i - 1;
            double w = 0.0;
            if (t == 2 * ip)     w += wid[ip];
            if (t == 2 * ip + 1) w += 4.0 * wid[ip];
            if (t == 2 * ip + 2) w += wid[ip];
            acc += w;
            Rl[t * NB + i] = acc;
        }
    }
    __syncthreads();

    // Q = R @ Phi_inv  (63 x 32)
    for (int f = t; f < MM * NB; f += 64) {
        int m = f >> 5, j = f & 31;
        double s = 0.0;
        for (int i = 0; i < NB; i++) s += Rl[m * NB + i] * aug[i * 64 + 32 + j];
        ws[OFF_Q + f] = (float)s;
    }
    // u[j] = sum_i Phi_inv[i][j]
    if (t < NB) {
        double s = 0.0;
        for (int i = 0; i < NB; i++) s += aug[i * 64 + 32 + t];
        ws[OFF_U + t] = (float)s;
    }
    // Phi_out (32 x 16)
    if (t < TT) {
        double x = -1.0 + 2.0 * ((double)t_span[t] - t0) / (t1 - t0);
        double r0 = 1.0, r1 = x;
        ws[OFF_PHIOUT + 0 * TT + t] = 1.0f;
        ws[OFF_PHIOUT + 1 * TT + t] = (float)x;
        for (int n = 2; n < NB; n++) {
            double r2 = 2.0 * x * r1 - r0;
            ws[OFF_PHIOUT + n * TT + t] = (float)r2;
            r0 = r1; r1 = r2;
        }
    }
}

// ---------------------------------------------------------------------------
// K1: G[n][h]=sum_d Bc[b,d,n]*W1[d,h] (tile 32x64), then per m-chunk:
//     h=tanh(G^T Phi_f + t*b1) in LDS, accumulate P[b,h,j]=sum_m h*Q[m,j]
// ---------------------------------------------------------------------------
__global__ __launch_bounds__(256) void k1_kernel(
        const float* __restrict__ Bc,   // (B, D, 32)
        const float* __restrict__ W1,   // (D, H)
        const float* __restrict__ b1,   // (H)
        float* __restrict__ ws) {
    __shared__ float a_s[32 * 34];      // [dd][n]
    __shared__ float w_s[32 * 68];      // [dd][h]
    __shared__ float g_s[32 * 65];      // [n][h]
    __shared__ float phif_s[NB * MM];
    __shared__ float q_s[MM * NB];
    __shared__ float ttrue_s[MM];
    __shared__ float htile_s[64 * 17];  // [h][mm]

    const int t = threadIdx.x;
    const int h0 = blockIdx.x * 64;
    const int b  = blockIdx.y;

    for (int f = t; f < NB * MM; f += 256) {
        phif_s[f] = ws[OFF_PHIF + f];
        q_s[f]    = ws[OFF_Q + f];
    }
    if (t < MM) ttrue_s[t] = ws[OFF_TTRUE + t];

    // ---- phase A: G tile ----
    float acc[2][4] = {{0.f,0.f,0.f,0.f},{0.f,0.f,0.f,0.f}};
    const int tn = t >> 4;       // 0..15
    const int th = t & 15;       // 0..15
    const int n0 = tn * 2;
    const int hl = th * 4;
    const float* BcB = Bc + (size_t)b * (DD * NB);

    for (int d0 = 0; d0 < DD; d0 += 32) {
        {
            int f = t;
            #pragma unroll
            for (int i = 0; i < 4; i++, f += 256) {
                int dd = f >> 5, n = f & 31;
                a_s[dd * 34 + n] = BcB[(size_t)(d0 + dd) * NB + n];
            }
        }
        {
            int f = t;
            #pragma unroll
            for (int i = 0; i < 8; i++, f += 256) {
                int dd = f >> 6, h = f & 63;
                w_s[dd * 68 + h] = W1[(size_t)(d0 + dd) * HH + h0 + h];
            }
        }
        __syncthreads();
        #pragma unroll
        for (int dd = 0; dd < 32; dd++) {
            float a0 = a_s[dd * 34 + n0];
            float a1 = a_s[dd * 34 + n0 + 1];
            float w0 = w_s[dd * 68 + hl + 0];
            float w1 = w_s[dd * 68 + hl + 1];
            float w2 = w_s[dd * 68 + hl + 2];
            float w3 = w_s[dd * 68 + hl + 3];
            acc[0][0] += a0 * w0; acc[0][1] += a0 * w1;
            acc[0][2] += a0 * w2; acc[0][3] += a0 * w3;
            acc[1][0] += a1 * w0; acc[1][1] += a1 * w1;
            acc[1][2] += a1 * w2; acc[1][3] += a1 * w3;
        }
        __syncthreads();
    }
    #pragma unroll
    for (int q = 0; q < 2; q++)
        #pragma unroll
        for (int r = 0; r < 4; r++)
            g_s[(n0 + q) * 65 + hl + r] = acc[q][r];
    __syncthreads();

    // ---- phase B: expand to simpson grid, tanh, contract with Q ----
    float pacc[8] = {0.f,0.f,0.f,0.f,0.f,0.f,0.f,0.f};
    const int ph  = t >> 2;           // 0..63
    const int pj0 = (t & 3) * 8;      // 0,8,16,24

    for (int mc = 0; mc < 4; mc++) {
        int m0 = mc * 16;
        int mlen = (MM - m0) < 16 ? (MM - m0) : 16;
        {
            int f = t;
            #pragma unroll
            for (int i = 0; i < 4; i++, f += 256) {
                int hl2 = f >> 4, mm = f & 15;
                int m = m0 + mm;
                if (m < MM) {
                    float z = 0.f;
                    #pragma unroll
                    for (int n = 0; n < NB; n++)
                        z += g_s[n * 65 + hl2] * phif_s[n * MM + m];
                    z += ttrue_s[m] * b1[h0 + hl2];
                    htile_s[hl2 * 17 + mm] = tanhf(z);
                }
            }
        }
        __syncthreads();
        for (int mm = 0; mm < mlen; mm++) {
            float hv = htile_s[ph * 17 + mm];
            const float* qr = q_s + (m0 + mm) * NB + pj0;
            #pragma unroll
            for (int jj = 0; jj < 8; jj++) pacc[jj] += hv * qr[jj];
        }
        __syncthreads();
    }

    float* P = ws + OFF_P;
    size_t base = ((size_t)b * HH + h0 + ph) * NB + pj0;
    float4 v0 = make_float4(pacc[0], pacc[1], pacc[2], pacc[3]);
    float4 v1 = make_float4(pacc[4], pacc[5], pacc[6], pacc[7]);
    *(float4*)(P + base)     = v0;
    *(float4*)(P + base + 4) = v1;
}

// ---------------------------------------------------------------------------
// K2: Bn[b,d,j] = sum_h W2[h,d] * P[b,h,j] + y_init[b,d]*u[j]
// ---------------------------------------------------------------------------
__global__ __launch_bounds__(256) void k2_kernel(
        const float* __restrict__ W2,     // (H, D)
        const float* __restrict__ y_init, // (B, D)
        float* __restrict__ ws) {
    __shared__ float wd_s[32 * 68];   // [hh][dl]
    __shared__ float p_s[32 * 34];    // [hh][j]
    __shared__ float u_s[NB];

    const int t = threadIdx.x;
    const int d0 = blockIdx.x * 64;
    const int b  = blockIdx.y;
    if (t < NB) u_s[t] = ws[OFF_U + t];

    const float* P = ws + OFF_P + (size_t)b * HH * NB;
    float acc[4][2] = {{0.f,0.f},{0.f,0.f},{0.f,0.f},{0.f,0.f}};
    const int td = t >> 4, tj = t & 15;
    const int dl0 = td * 4, j0 = tj * 2;

    for (int h0c = 0; h0c < HH; h0c += 32) {
        {
            int f = t;
            #pragma unroll
            for (int i = 0; i < 8; i++, f += 256) {
                int hh = f >> 6, dl = f & 63;
                wd_s[hh * 68 + dl] = W2[(size_t)(h0c + hh) * DD + d0 + dl];
            }
        }
        {
            int f = t;
            #pragma unroll
            for (int i = 0; i < 4; i++, f += 256) {
                int hh = f >> 5, j = f & 31;
                p_s[hh * 34 + j] = P[(size_t)(h0c + hh) * NB + j];
            }
        }
        __syncthreads();
        #pragma unroll
        for (int hh = 0; hh < 32; hh++) {
            float p0 = p_s[hh * 34 + j0];
            float p1 = p_s[hh * 34 + j0 + 1];
            float w0 = wd_s[hh * 68 + dl0 + 0];
            float w1 = wd_s[hh * 68 + dl0 + 1];
            float w2 = wd_s[hh * 68 + dl0 + 2];
            float w3 = wd_s[hh * 68 + dl0 + 3];
            acc[0][0] += w0 * p0; acc[0][1] += w0 * p1;
            acc[1][0] += w1 * p0; acc[1][1] += w1 * p1;
            acc[2][0] += w2 * p0; acc[2][1] += w2 * p1;
            acc[3][0] += w3 * p0; acc[3][1] += w3 * p1;
        }
        __syncthreads();
    }

    float* Bn = ws + OFF_BCUR;
    #pragma unroll
    for (int q = 0; q < 4; q++) {
        int d = d0 + dl0 + q;
        float y = y_init[(size_t)b * DD + d];
        size_t base = ((size_t)b * DD + d) * NB + j0;
        Bn[base]     = acc[q][0] + y * u_s[j0];
        Bn[base + 1] = acc[q][1] + y * u_s[j0 + 1];
    }
}

// ---------------------------------------------------------------------------
// K3: out0[t,b,d] = sum_n Bcur[b,d,n]*Phi_out[n,t] ; out1 = Bcur
// ---------------------------------------------------------------------------
__global__ __launch_bounds__(256) void k3_kernel(
        const float* __restrict__ ws_c, float* __restrict__ out) {
    __shared__ float rows_s[64 * 33];    // padded: bank = (rl+n)%32
    __shared__ float phiout_s[NB * TT];

    const int t = threadIdx.x;
    const int r0 = blockIdx.x * 64;
    const float* Bf = ws_c + OFF_BCUR;

    for (int f = t; f < NB * TT; f += 256) phiout_s[f] = ws_c[OFF_PHIOUT + f];

    float vals[8];
    {
        int f = t;
        #pragma unroll
        for (int i = 0; i < 8; i++, f += 256) {
            float v = Bf[(size_t)r0 * NB + f];
            rows_s[(f >> 5) * 33 + (f & 31)] = v;
            vals[i] = v;
        }
    }
    // out1 copy
    float* out1 = out + (size_t)TT * BB * DD;
    {
        int f = t;
        #pragma unroll
        for (int i = 0; i < 8; i++, f += 256) out1[(size_t)r0 * NB + f] = vals[i];
    }
    __syncthreads();

    #pragma unroll
    for (int i = 0; i < 4; i++) {
        int idx = i * 256 + t;          // tt*64 + rl
        int tt = idx >> 6, rl = idx & 63;
        float s = 0.f;
        #pragma unroll
        for (int n = 0; n < NB; n++)
            s += rows_s[rl * 33 + n] * phiout_s[n * TT + tt];
        out[(size_t)tt * (BB * DD) + r0 + rl] = s;
    }
}

// ---------------------------------------------------------------------------
extern "C" void kernel_launch(void* const* d_in, const int* in_sizes, int n_in,
                              void* d_out, int out_size, void* d_ws, size_t ws_size,
                              hipStream_t stream) {
    const float* t_span = (const float*)d_in[0];
    const float* y_init = (const float*)d_in[1];
    const float* B_init = (const float*)d_in[2];
    const float* W1     = (const float*)d_in[3];
    const float* b1     = (const float*)d_in[4];
    const float* W2     = (const float*)d_in[5];
    float* ws  = (float*)d_ws;
    float* out = (float*)d_out;

    setup_kernel<<<1, 64, 0, stream>>>(t_span, ws);

    for (int it = 0; it < ITERS; it++) {
        const float* src = (it == 0) ? B_init : (ws + OFF_BCUR);
        k1_kernel<<<dim3(HH / 64, BB), 256, 0, stream>>>(src, W1, b1, ws);
        k2_kernel<<<dim3(DD / 64, BB), 256, 0, stream>>>(W2, y_init, ws);
    }
    k3_kernel<<<dim3((BB * DD) / 64), 256, 0, stream>>>(ws, out);
}

// Round 2
// 890.701 us; speedup vs baseline: 3.8846x; 3.8846x over previous
//
#include <hip/hip_runtime.h>
#include <hip/hip_bf16.h>
#include <math.h>

// Problem constants (fixed by setup_inputs)
#define BB 128
#define DD 512
#define HH 1024
#define NB 32     // num_coeff_per_dim
#define MM 63     // 2N-1 simpson points
#define TT 16
#define ITERS 10

// ws layout (float units)
#define OFF_U       0        // 32 fp32
#define OFF_TTRUE   64       // 64 fp32 (tt[63]=0)
#define OFF_PHIOUT  128      // 512 fp32
#define OFF_PHIF_BF 1024     // bf16 [64 m][32 n]  (row 63 = 0)   = 1024 floats
#define OFF_QT_BF   2048     // bf16 [32 j][64 m]  (col 63 = 0)   = 1024 floats
#define HDRF        4096
#define OFF_BN      HDRF                     // fp32 [B][512][32]  = 2097152
#define OFF_BCT     (OFF_BN + 2097152)       // bf16 [B][32][512]  = 1048576 f
#define OFF_PT      (OFF_BCT + 1048576)      // bf16 [B][32][1024] = 2097152 f
#define OFF_W1T     (OFF_PT + 2097152)       // bf16 [1024][512]   = 262144 f
#define OFF_W2T     (OFF_W1T + 262144)       // bf16 [512][1024]   = 262144 f
// end = 5771264 floats = 23.1 MB

typedef __attribute__((ext_vector_type(8))) short bf16x8;
typedef __attribute__((ext_vector_type(4))) float f32x4;

static __device__ __forceinline__ unsigned short f2bf(float f) {
    unsigned int x = __builtin_bit_cast(unsigned int, f);
    unsigned int r = x + 0x7FFFu + ((x >> 16) & 1u);   // RNE
    return (unsigned short)(r >> 16);
}

static __device__ __forceinline__ void store4bf(unsigned short* p,
                                                float v0, float v1, float v2, float v3) {
    unsigned int lo = (unsigned int)f2bf(v0) | ((unsigned int)f2bf(v1) << 16);
    unsigned int hi = (unsigned int)f2bf(v2) | ((unsigned int)f2bf(v3) << 16);
    uint2 u; u.x = lo; u.y = hi;
    *(uint2*)p = u;   // 8B-aligned by construction
}

static __device__ __forceinline__ float tanh_fast(float x) {
    // tanh(x) = 1 - 2/(exp(2x)+1); robust at +/-inf, ~1e-6 rel error
    float e = exp2f(x * 2.88539008177793f);   // 2*log2(e)
    return 1.0f - 2.0f / (e + 1.0f);
}

// ---------------------------------------------------------------------------
// Setup: t grids, Phi_f, Phi_inv (double GJ), Q = R@Phi_inv, u, Phi_out,
// bf16 tables phif_bf [m][n] and qt_bf [j][m]
// ---------------------------------------------------------------------------
__global__ void setup_kernel(const float* __restrict__ t_span,
                             float* __restrict__ ws) {
    __shared__ double tsim[MM];
    __shared__ double ttrue_d[MM];
    __shared__ double wid[31];
    __shared__ double phid[NB * MM];   // [n][m]
    __shared__ double aug[NB * 64];    // [Phi | I]
    __shared__ double mlt[NB];
    __shared__ double Rl[MM * NB];
    __shared__ double Qd[MM * NB];     // [m][j]
    __shared__ int    piv_s;
    __shared__ double pv_s;

    const int t = threadIdx.x;  // 64 threads
    const double PI = 3.14159265358979323846;
    const double t0 = (double)t_span[0];
    const double t1 = (double)t_span[TT - 1];

    if (t < MM) {
        double v;
        if ((t & 1) == 0) {
            int j = t >> 1;
            v = -cos(PI * (double)j / (double)(NB - 1));
        } else {
            int i = t >> 1;
            double a = -cos(PI * (double)i / (double)(NB - 1));
            double b = -cos(PI * (double)(i + 1) / (double)(NB - 1));
            v = 0.5 * (a + b);
        }
        tsim[t] = v;
        ttrue_d[t] = t0 + 0.5 * (t1 - t0) * (v + 1.0);
    }
    __syncthreads();
    if (t < 31) wid[t] = (ttrue_d[2 * t + 2] - ttrue_d[2 * t]) / 6.0;
    if (t < MM) ws[OFF_TTRUE + t] = (float)ttrue_d[t];
    if (t == 63) ws[OFF_TTRUE + 63] = 0.0f;

    if (t < MM) {
        double x = tsim[t];
        double r0 = 1.0, r1 = x;
        phid[0 * MM + t] = r0;
        phid[1 * MM + t] = r1;
        for (int n = 2; n < NB; n++) {
            double r2 = 2.0 * x * r1 - r0;
            phid[n * MM + t] = r2;
            r0 = r1; r1 = r2;
        }
    }
    __syncthreads();

    // phif_bf [m 64][n 32], row 63 = 0
    {
        unsigned short* pf = (unsigned short*)(ws + OFF_PHIF_BF);
        for (int f = t; f < 64 * 32; f += 64) {
            int m = f >> 5, n = f & 31;
            pf[f] = f2bf(m < MM ? (float)phid[n * MM + m] : 0.0f);
        }
    }

    // augmented [Phi | I], Phi[r][c] = phid[r*MM + 2c]
    for (int f = t; f < NB * 64; f += 64) {
        int r = f >> 6, c = f & 63;
        double v;
        if (c < NB) v = phid[r * MM + 2 * c];
        else        v = ((c - NB) == r) ? 1.0 : 0.0;
        aug[f] = v;
    }
    __syncthreads();

    for (int k = 0; k < NB; k++) {
        if (t == 0) {
            int p = k;
            double best = fabs(aug[k * 64 + k]);
            for (int r = k + 1; r < NB; r++) {
                double v = fabs(aug[r * 64 + k]);
                if (v > best) { best = v; p = r; }
            }
            piv_s = p;
        }
        __syncthreads();
        int p = piv_s;
        if (p != k) {
            double tmp = aug[k * 64 + t];
            aug[k * 64 + t] = aug[p * 64 + t];
            aug[p * 64 + t] = tmp;
        }
        __syncthreads();
        if (t == 0) pv_s = aug[k * 64 + k];
        __syncthreads();
        aug[k * 64 + t] /= pv_s;
        __syncthreads();
        if (t < NB) mlt[t] = aug[t * 64 + k];
        __syncthreads();
        for (int r = 0; r < NB; r++) {
            if (r != k) aug[r * 64 + t] -= mlt[r] * aug[k * 64 + t];
        }
        __syncthreads();
    }
    // Phi_inv[i][j] = aug[i*64 + 32 + j]

    if (t < MM) {
        double acc = 0.0;
        Rl[t * NB + 0] = 0.0;
        for (int i = 1; i < NB; i++) {
            int ip = i - 1;
            double w = 0.0;
            if (t == 2 * ip)     w += wid[ip];
            if (t == 2 * ip + 1) w += 4.0 * wid[ip];
            if (t == 2 * ip + 2) w += wid[ip];
            acc += w;
            Rl[t * NB + i] = acc;
        }
    }
    __syncthreads();

    // Qd = R @ Phi_inv  (63 x 32)
    for (int f = t; f < MM * NB; f += 64) {
        int m = f >> 5, j = f & 31;
        double s = 0.0;
        for (int i = 0; i < NB; i++) s += Rl[m * NB + i] * aug[i * 64 + 32 + j];
        Qd[f] = s;
    }
    __syncthreads();

    // qt_bf [j 32][m 64], col 63 = 0
    {
        unsigned short* qt = (unsigned short*)(ws + OFF_QT_BF);
        for (int f = t; f < 32 * 64; f += 64) {
            int j = f >> 6, m = f & 63;
            qt[f] = f2bf(m < MM ? (float)Qd[m * NB + j] : 0.0f);
        }
    }
    // u[j] = sum_i Phi_inv[i][j]
    if (t < NB) {
        double s = 0.0;
        for (int i = 0; i < NB; i++) s += aug[i * 64 + 32 + t];
        ws[OFF_U + t] = (float)s;
    }
    // Phi_out (32 x 16)
    if (t < TT) {
        double x = -1.0 + 2.0 * ((double)t_span[t] - t0) / (t1 - t0);
        double r0 = 1.0, r1 = x;
        ws[OFF_PHIOUT + 0 * TT + t] = 1.0f;
        ws[OFF_PHIOUT + 1 * TT + t] = (float)x;
        for (int n = 2; n < NB; n++) {
            double r2 = 2.0 * x * r1 - r0;
            ws[OFF_PHIOUT + n * TT + t] = (float)r2;
            r0 = r1; r1 = r2;
        }
    }
}

// ---------------------------------------------------------------------------
// Transpose fp32 (R x C) -> bf16 (C x R)
// ---------------------------------------------------------------------------
__global__ __launch_bounds__(256) void transpose_f32_bf16(
        const float* __restrict__ in, unsigned short* __restrict__ out,
        int R, int C) {
    __shared__ float tile[32][33];
    const int t = threadIdx.x;
    const int tc = blockIdx.x, tr = blockIdx.y;
    const int c = tc * 32 + (t & 31);
    #pragma unroll
    for (int i = 0; i < 4; i++) {
        int rl = (t >> 5) + i * 8;
        tile[rl][t & 31] = in[(size_t)(tr * 32 + rl) * C + c];
    }
    __syncthreads();
    #pragma unroll
    for (int i = 0; i < 4; i++) {
        int orl = (t >> 5) + i * 8;            // local col of input
        int orow = tc * 32 + orl;
        int ocol = tr * 32 + (t & 31);
        out[(size_t)orow * R + ocol] = f2bf(tile[t & 31][orl]);
    }
}

// B_init [b][d][n] fp32 -> Bct [b][n][d] bf16
__global__ __launch_bounds__(256) void binit_kernel(
        const float* __restrict__ Bi, unsigned short* __restrict__ Bct) {
    __shared__ float tile[32][33];
    const int t = threadIdx.x;
    const int b = blockIdx.y, d0 = blockIdx.x * 32;
    #pragma unroll
    for (int i = 0; i < 4; i++) {
        int f = i * 256 + t;
        int dd = f >> 5, n = f & 31;
        tile[dd][n] = Bi[((size_t)b * DD + d0 + dd) * NB + n];
    }
    __syncthreads();
    #pragma unroll
    for (int i = 0; i < 4; i++) {
        int f = i * 256 + t;
        int n = f >> 5, dd = f & 31;
        Bct[((size_t)b * NB + n) * DD + d0 + dd] = f2bf(tile[dd][n]);
    }
}

// ---------------------------------------------------------------------------
// K1: per block (b, 128 h). Phase A: G[n=32][h=128] = Bc^T W1 via MFMA.
// Phase B: Z = Phi_f^T G (MFMA), tanh, P = Q^T T (MFMA). All LDS wave-private.
// ---------------------------------------------------------------------------
__global__ __launch_bounds__(256) void k1_kernel(
        const unsigned short* __restrict__ Bct,  // [B][32 n][512 d] bf16
        const unsigned short* __restrict__ W1t,  // [1024 h][512 d] bf16
        const float* __restrict__ b1,            // [1024]
        const float* __restrict__ ws,
        unsigned short* __restrict__ Pt)         // [B][32 j][1024 h] bf16
{
    __shared__ unsigned short g_sb[128 * 32];    // [h_loc][n]
    __shared__ unsigned short t_sb[128 * 72];    // [h_loc][m], stride 72 (pad)

    const int t    = threadIdx.x;
    const int lane = t & 63;
    const int w    = t >> 6;       // wave 0..3
    const int q    = lane >> 4;    // quad 0..3
    const int l15  = lane & 15;
    const int b    = blockIdx.y;
    const int h0   = blockIdx.x * 128;
    const int hw   = h0 + w * 32;  // wave's global h base

    // ---- Phase A: G = Bc^T W1, M=32(n) x N=32(h per wave) x K=512 ----
    f32x4 acc[2][2] = {};
    const unsigned short* A0 = Bct + (size_t)b * NB * DD;
    #pragma unroll 4
    for (int d0 = 0; d0 < DD; d0 += 32) {
        bf16x8 a0 = *(const bf16x8*)(A0 + (size_t)(l15) * DD + d0 + q * 8);
        bf16x8 a1 = *(const bf16x8*)(A0 + (size_t)(16 + l15) * DD + d0 + q * 8);
        bf16x8 bb0 = *(const bf16x8*)(W1t + (size_t)(hw + l15) * DD + d0 + q * 8);
        bf16x8 bb1 = *(const bf16x8*)(W1t + (size_t)(hw + 16 + l15) * DD + d0 + q * 8);
        acc[0][0] = __builtin_amdgcn_mfma_f32_16x16x32_bf16(a0, bb0, acc[0][0], 0, 0, 0);
        acc[0][1] = __builtin_amdgcn_mfma_f32_16x16x32_bf16(a0, bb1, acc[0][1], 0, 0, 0);
        acc[1][0] = __builtin_amdgcn_mfma_f32_16x16x32_bf16(a1, bb0, acc[1][0], 0, 0, 0);
        acc[1][1] = __builtin_amdgcn_mfma_f32_16x16x32_bf16(a1, bb1, acc[1][1], 0, 0, 0);
    }
    // write G to g_sb[h_loc][n] as bf16 (C-layout: row n = mt*16+q*4+r, col h = l15)
    #pragma unroll
    for (int mt = 0; mt < 2; mt++)
        #pragma unroll
        for (int nt = 0; nt < 2; nt++) {
            int hl = w * 32 + nt * 16 + l15;
            store4bf(&g_sb[hl * 32 + mt * 16 + q * 4],
                     acc[mt][nt][0], acc[mt][nt][1], acc[mt][nt][2], acc[mt][nt][3]);
        }
    __syncthreads();

    // ---- Z = Phi_f^T G : M=64(m) x N=32(h/wave) x K=32(n), 1 K-step ----
    f32x4 zacc[4][2] = {};
    const unsigned short* PF = (const unsigned short*)(ws + OFF_PHIF_BF);
    bf16x8 gb[2];
    #pragma unroll
    for (int nt = 0; nt < 2; nt++)
        gb[nt] = *(const bf16x8*)(&g_sb[(w * 32 + nt * 16 + l15) * 32 + q * 8]);
    #pragma unroll
    for (int mt = 0; mt < 4; mt++) {
        bf16x8 af = *(const bf16x8*)(PF + (mt * 16 + l15) * 32 + q * 8);
        zacc[mt][0] = __builtin_amdgcn_mfma_f32_16x16x32_bf16(af, gb[0], zacc[mt][0], 0, 0, 0);
        zacc[mt][1] = __builtin_amdgcn_mfma_f32_16x16x32_bf16(af, gb[1], zacc[mt][1], 0, 0, 0);
    }

    // bias + tanh + write t_sb[h_loc][m] bf16
    const float* TTp = ws + OFF_TTRUE;
    float b1v[2] = { b1[hw + l15], b1[hw + 16 + l15] };
    #pragma unroll
    for (int mt = 0; mt < 4; mt++) {
        float4 ttv = *(const float4*)(TTp + mt * 16 + q * 4);
        #pragma unroll
        for (int nt = 0; nt < 2; nt++) {
            int hl = w * 32 + nt * 16 + l15;
            float v0 = tanh_fast(zacc[mt][nt][0] + ttv.x * b1v[nt]);
            float v1 = tanh_fast(zacc[mt][nt][1] + ttv.y * b1v[nt]);
            float v2 = tanh_fast(zacc[mt][nt][2] + ttv.z * b1v[nt]);
            float v3 = tanh_fast(zacc[mt][nt][3] + ttv.w * b1v[nt]);
            store4bf(&t_sb[hl * 72 + mt * 16 + q * 4], v0, v1, v2, v3);
        }
    }
    __syncthreads();

    // ---- P = Q^T T : M=32(j) x N=32(h/wave) x K=64(m), 2 K-steps ----
    f32x4 pacc[2][2] = {};
    const unsigned short* QT = (const unsigned short*)(ws + OFF_QT_BF);
    #pragma unroll
    for (int ks = 0; ks < 2; ks++) {
        bf16x8 bt[2];
        #pragma unroll
        for (int nt = 0; nt < 2; nt++)
            bt[nt] = *(const bf16x8*)(&t_sb[(w * 32 + nt * 16 + l15) * 72 + ks * 32 + q * 8]);
        #pragma unroll
        for (int jt = 0; jt < 2; jt++) {
            bf16x8 aq = *(const bf16x8*)(QT + (jt * 16 + l15) * 64 + ks * 32 + q * 8);
            pacc[jt][0] = __builtin_amdgcn_mfma_f32_16x16x32_bf16(aq, bt[0], pacc[jt][0], 0, 0, 0);
            pacc[jt][1] = __builtin_amdgcn_mfma_f32_16x16x32_bf16(aq, bt[1], pacc[jt][1], 0, 0, 0);
        }
    }

    // store P_t[b][j][h] bf16
    #pragma unroll
    for (int jt = 0; jt < 2; jt++)
        #pragma unroll
        for (int nt = 0; nt < 2; nt++) {
            int hg = hw + nt * 16 + l15;
            #pragma unroll
            for (int r = 0; r < 4; r++) {
                int j = jt * 16 + q * 4 + r;
                Pt[((size_t)b * NB + j) * HH + hg] = f2bf(pacc[jt][nt][r]);
            }
        }
}

// ---------------------------------------------------------------------------
// K2: Bn[b,d,j] = sum_h P[b,h,j] W2[h,d] + y u[j]  via MFMA
//     M=32(j) x N=128(d per block) x K=1024(h)
// ---------------------------------------------------------------------------
__global__ __launch_bounds__(256) void k2_kernel(
        const unsigned short* __restrict__ Pt,   // [B][32 j][1024 h] bf16
        const unsigned short* __restrict__ W2t,  // [512 d][1024 h] bf16
        const float* __restrict__ y_init,        // [B][512]
        const float* __restrict__ ws,
        float* __restrict__ Bn,                  // [B][512][32] fp32
        unsigned short* __restrict__ Bct)        // [B][32][512] bf16 (next iter)
{
    __shared__ float ls[4][32 * 33];

    const int t    = threadIdx.x;
    const int lane = t & 63;
    const int w    = t >> 6;
    const int q    = lane >> 4;
    const int l15  = lane & 15;
    const int b    = blockIdx.y;
    const int d0   = blockIdx.x * 128;
    const int dw   = d0 + w * 32;

    f32x4 acc[2][2] = {};
    const unsigned short* A0 = Pt + (size_t)b * NB * HH;
    #pragma unroll 4
    for (int h0c = 0; h0c < HH; h0c += 32) {
        bf16x8 a0 = *(const bf16x8*)(A0 + (size_t)(l15) * HH + h0c + q * 8);
        bf16x8 a1 = *(const bf16x8*)(A0 + (size_t)(16 + l15) * HH + h0c + q * 8);
        bf16x8 bb0 = *(const bf16x8*)(W2t + (size_t)(dw + l15) * HH + h0c + q * 8);
        bf16x8 bb1 = *(const bf16x8*)(W2t + (size_t)(dw + 16 + l15) * HH + h0c + q * 8);
        acc[0][0] = __builtin_amdgcn_mfma_f32_16x16x32_bf16(a0, bb0, acc[0][0], 0, 0, 0);
        acc[0][1] = __builtin_amdgcn_mfma_f32_16x16x32_bf16(a0, bb1, acc[0][1], 0, 0, 0);
        acc[1][0] = __builtin_amdgcn_mfma_f32_16x16x32_bf16(a1, bb0, acc[1][0], 0, 0, 0);
        acc[1][1] = __builtin_amdgcn_mfma_f32_16x16x32_bf16(a1, bb1, acc[1][1], 0, 0, 0);
    }

    // epilogue: add y*u, write Bct (bf16, [b][j][d]) and stage for fp32 Bn
    const float* U = ws + OFF_U;
    float yv[2] = { y_init[(size_t)b * DD + dw + l15],
                    y_init[(size_t)b * DD + dw + 16 + l15] };
    #pragma unroll
    for (int mt = 0; mt < 2; mt++) {
        float4 uv = *(const float4*)(U + mt * 16 + q * 4);
        #pragma unroll
        for (int nt = 0; nt < 2; nt++) {
            int dl = nt * 16 + l15;         // 0..31 within wave
            #pragma unroll
            for (int r = 0; r < 4; r++) {
                int j = mt * 16 + q * 4 + r;
                float uvr = (r == 0) ? uv.x : (r == 1) ? uv.y : (r == 2) ? uv.z : uv.w;
                float val = acc[mt][nt][r] + yv[nt] * uvr;
                Bct[((size_t)b * NB + j) * DD + dw + dl] = f2bf(val);
                ls[w][j * 33 + dl] = val;
            }
        }
    }
    __syncthreads();
    // coalesced fp32 Bn write: [b][d][j]
    #pragma unroll
    for (int it = 0; it < 16; it++) {
        int f = it * 64 + lane;
        int d_l = f >> 5, j2 = f & 31;
        Bn[((size_t)b * DD + dw + d_l) * NB + j2] = ls[w][j2 * 33 + d_l];
    }
}

// ---------------------------------------------------------------------------
// K3: out0[t,b,d] = sum_n Bn[b,d,n]*Phi_out[n,t] ; out1 = Bn
// ---------------------------------------------------------------------------
__global__ __launch_bounds__(256) void k3_kernel(
        const float* __restrict__ ws_c, float* __restrict__ out) {
    __shared__ float rows_s[64 * 33];
    __shared__ float phiout_s[NB * TT];

    const int t = threadIdx.x;
    const int r0 = blockIdx.x * 64;
    const float* Bf = ws_c + OFF_BN;

    for (int f = t; f < NB * TT; f += 256) phiout_s[f] = ws_c[OFF_PHIOUT + f];

    float vals[8];
    {
        int f = t;
        #pragma unroll
        for (int i = 0; i < 8; i++, f += 256) {
            float v = Bf[(size_t)r0 * NB + f];
            rows_s[(f >> 5) * 33 + (f & 31)] = v;
            vals[i] = v;
        }
    }
    float* out1 = out + (size_t)TT * BB * DD;
    {
        int f = t;
        #pragma unroll
        for (int i = 0; i < 8; i++, f += 256) out1[(size_t)r0 * NB + f] = vals[i];
    }
    __syncthreads();

    #pragma unroll
    for (int i = 0; i < 4; i++) {
        int idx = i * 256 + t;
        int tt = idx >> 6, rl = idx & 63;
        float s = 0.f;
        #pragma unroll
        for (int n = 0; n < NB; n++)
            s += rows_s[rl * 33 + n] * phiout_s[n * TT + tt];
        out[(size_t)tt * (BB * DD) + r0 + rl] = s;
    }
}

// ---------------------------------------------------------------------------
extern "C" void kernel_launch(void* const* d_in, const int* in_sizes, int n_in,
                              void* d_out, int out_size, void* d_ws, size_t ws_size,
                              hipStream_t stream) {
    const float* t_span = (const float*)d_in[0];
    const float* y_init = (const float*)d_in[1];
    const float* B_init = (const float*)d_in[2];
    const float* W1     = (const float*)d_in[3];
    const float* b1     = (const float*)d_in[4];
    const float* W2     = (const float*)d_in[5];
    float* ws  = (float*)d_ws;
    float* out = (float*)d_out;

    unsigned short* W1t = (unsigned short*)(ws + OFF_W1T);
    unsigned short* W2t = (unsigned short*)(ws + OFF_W2T);
    unsigned short* Bct = (unsigned short*)(ws + OFF_BCT);
    unsigned short* Pt  = (unsigned short*)(ws + OFF_PT);
    float*          Bn  = ws + OFF_BN;

    setup_kernel<<<1, 64, 0, stream>>>(t_span, ws);
    transpose_f32_bf16<<<dim3(HH / 32, DD / 32), 256, 0, stream>>>(W1, W1t, DD, HH);
    transpose_f32_bf16<<<dim3(DD / 32, HH / 32), 256, 0, stream>>>(W2, W2t, HH, DD);
    binit_kernel<<<dim3(DD / 32, BB), 256, 0, stream>>>(B_init, Bct);

    for (int it = 0; it < ITERS; it++) {
        k1_kernel<<<dim3(HH / 128, BB), 256, 0, stream>>>(Bct, W1t, b1, ws, Pt);
        k2_kernel<<<dim3(DD / 128, BB), 256, 0, stream>>>(Pt, W2t, y_init, ws, Bn, Bct);
    }
    k3_kernel<<<dim3((BB * DD) / 64), 256, 0, stream>>>(ws, out);
}